// Round 7
// baseline (362.257 us; speedup 1.0000x reference)
//
#include <hip/hip_runtime.h>

// GroupTokenizer: y [B,T,C] f32, edges [C,K] f32 -> labels [B,T,C] (as f32), reg [B,T,C,K] f32.
// B=32 T=4096 C=8 K=64. Output = 272.6 MB streaming stores.
//
// R7 = MEASUREMENT ROUND. R4/R5/R6 (three different store structures) all give
// dur_us - poisonfill ~= 93-106 us, but session clock drift (~15%) makes cross-round
// residuals untrustworthy, and the top-5 profile filter hides the kernel dispatch
// (all rows are >=170 us harness fills). So: launch the identical kernel 3x
// (idempotent, same values). Delta(dur_us)/2 = true per-launch kernel time,
// measured under the same clocks. ~45 us => kernel at write roofline (residual is
// harness); ~100 us => 2.4x real headroom remains.
#define N_ELEM (32 * 4096 * 8)
#define CCH 8
#define KB 64

typedef float vfloat4 __attribute__((ext_vector_type(4)));

__global__ __launch_bounds__(256) void group_tokenizer_kernel(
    const float* __restrict__ y,
    const float* __restrict__ le,
    const float* __restrict__ re,
    float* __restrict__ out,
    int ngroups) {
  // Edges in LDS, stride K+1=65: bank = (c + k) % 32, distinct across channels;
  // same-channel lanes read identical addresses -> broadcast (free).
  __shared__ float ls[CCH][KB + 1];
  __shared__ float rs[CCH][KB + 1];
  const int tid = threadIdx.x;
  for (int t = tid; t < CCH * KB; t += blockDim.x) {
    ls[t >> 6][t & 63] = le[t];
    rs[t >> 6][t & 63] = re[t];
  }
  __syncthreads();

  const int lane = tid & 63;
  const int wid = tid >> 6;
  const int gwave = blockIdx.x * 4 + wid;
  const int nwaves = gridDim.x * 4;

  // Loop-invariant hoists.
  const int c = lane & (CCH - 1);          // e % 8 == lane % 8 (tile base % 64 == 0)
  const float* lr = ls[c];
  const float* rr = rs[c];
  const int kst = (lane & 15) << 2;        // this lane's k-offset within its element
  const int src_base = lane >> 4;

  for (int g = gwave; g < ngroups; g += nwaves) {
    const float yv = y[g * 64 + lane];

    // lower_bound on r: first k with yv < r[k]. 65 possible answers -> 7 branchless
    // steps (6 left a size-1 interval untested: round-2 absmax=2.0 bug).
    int lo = 0, hi = KB;
#pragma unroll
    for (int it = 0; it < 7; ++it) {
      const int mid = (lo + hi) >> 1;
      const bool cond = yv < rr[mid];
      hi = cond ? mid : hi;
      lo = cond ? lo : mid + 1;
    }
    // in_bin[lo] iff yv >= l[lo]; else no bin -> label K-1. (lo==KB read safe: padded.)
    const int label = (lo < KB && yv >= lr[lo]) ? lo : (KB - 1);

    const float left = lr[label];
    const float width = fmaxf(rr[label] - left, 1e-12f);
    const float delta = fminf(fmaxf((yv - left) / width, 0.0f), 1.0f);

    // labels output (as float), 256 B/wave coalesced full lines.
    out[g * 64 + lane] = (float)label;

    // reg tile: 64 elems * 64 bins = 16 KB contiguous per wave-iteration.
    // 16 fully-coalesced dwordx4 stores (1 KB/instr, full 128-B lines -> no RMW).
    vfloat4* regv = (vfloat4*)(out + (size_t)N_ELEM + (size_t)g * (64 * KB)) + lane;
#pragma unroll
    for (int j = 0; j < 16; ++j) {
      const int src = (j << 2) + src_base;      // which lane's element this float4 belongs to
      const int lbl = __shfl(label, src, 64);
      const float dlt = __shfl(delta, src, 64);
      vfloat4 v;
      v.x = (kst + 0 == lbl) ? dlt : -1.0f;
      v.y = (kst + 1 == lbl) ? dlt : -1.0f;
      v.z = (kst + 2 == lbl) ? dlt : -1.0f;
      v.w = (kst + 3 == lbl) ? dlt : -1.0f;
      regv[j << 6] = v;
    }
  }
}

extern "C" void kernel_launch(void* const* d_in, const int* in_sizes, int n_in,
                              void* d_out, int out_size, void* d_ws, size_t ws_size,
                              hipStream_t stream) {
  const float* y = (const float*)d_in[0];
  const float* le = (const float*)d_in[1];
  const float* re = (const float*)d_in[2];
  float* out = (float*)d_out;

  const int n = in_sizes[0];          // 1048576
  const int ngroups = n / 64;         // 16384 wave-tiles
  const int blocks = 1024;            // 4096 waves, 4 tiles per wave (grid-stride)

  // MEASUREMENT: 3 identical idempotent launches. Delta(dur_us)/2 vs R6's single
  // launch = true kernel time under same-session clocks.
  group_tokenizer_kernel<<<blocks, 256, 0, stream>>>(y, le, re, out, ngroups);
  group_tokenizer_kernel<<<blocks, 256, 0, stream>>>(y, le, re, out, ngroups);
  group_tokenizer_kernel<<<blocks, 256, 0, stream>>>(y, le, re, out, ngroups);
}

// Round 8
// 276.850 us; speedup vs baseline: 1.3085x; 1.3085x over previous
//
#include <hip/hip_runtime.h>

// GroupTokenizer: y [B,T,C] f32, edges [C,K] f32 -> labels [B,T,C] (as f32), reg [B,T,C,K] f32.
// B=32 T=4096 C=8 K=64. Output = 272.6 MB streaming stores.
//
// ROOFLINE EVIDENCE (R7 measurement round): 3 identical launches cost dur_us
// 362.3 vs 277.0 for 1 launch => kernel = (362.3-277.0)/2 = 42.6 us/launch
// = 277.6 MB / 42.6 us = 6.5 TB/s, at the ceiling the harness's own
// fillBufferAligned proves for this buffer (6.3-6.5 TB/s, 79-81% of 8 TB/s spec).
// Remaining dur_us is harness re-poison fill (~170 us) + restore/launch (~64 us).
// Output bytes are mandatory (every byte fixed by reference semantics) => this is
// the memory roofline. Binary search + shuffle repack fully hidden under store drain.
#define N_ELEM (32 * 4096 * 8)
#define CCH 8
#define KB 64

typedef float vfloat4 __attribute__((ext_vector_type(4)));

__global__ __launch_bounds__(256) void group_tokenizer_kernel(
    const float* __restrict__ y,
    const float* __restrict__ le,
    const float* __restrict__ re,
    float* __restrict__ out,
    int ngroups) {
  // Edges in LDS, stride K+1=65: bank = (c + k) % 32, distinct across channels;
  // same-channel lanes read identical addresses -> broadcast (free).
  __shared__ float ls[CCH][KB + 1];
  __shared__ float rs[CCH][KB + 1];
  const int tid = threadIdx.x;
  for (int t = tid; t < CCH * KB; t += blockDim.x) {
    ls[t >> 6][t & 63] = le[t];
    rs[t >> 6][t & 63] = re[t];
  }
  __syncthreads();

  const int lane = tid & 63;
  const int wid = tid >> 6;
  const int gwave = blockIdx.x * 4 + wid;
  const int nwaves = gridDim.x * 4;

  // Loop-invariant hoists.
  const int c = lane & (CCH - 1);          // e % 8 == lane % 8 (tile base % 64 == 0)
  const float* lr = ls[c];
  const float* rr = rs[c];
  const int kst = (lane & 15) << 2;        // this lane's k-offset within its element
  const int src_base = lane >> 4;

  for (int g = gwave; g < ngroups; g += nwaves) {
    const float yv = y[g * 64 + lane];

    // lower_bound on r: first k with yv < r[k]. 65 possible answers -> 7 branchless
    // steps (6 left a size-1 interval untested: round-2 absmax=2.0 bug).
    int lo = 0, hi = KB;
#pragma unroll
    for (int it = 0; it < 7; ++it) {
      const int mid = (lo + hi) >> 1;
      const bool cond = yv < rr[mid];
      hi = cond ? mid : hi;
      lo = cond ? lo : mid + 1;
    }
    // in_bin[lo] iff yv >= l[lo]; else no bin -> label K-1. (lo==KB read safe: padded.)
    const int label = (lo < KB && yv >= lr[lo]) ? lo : (KB - 1);

    const float left = lr[label];
    const float width = fmaxf(rr[label] - left, 1e-12f);
    const float delta = fminf(fmaxf((yv - left) / width, 0.0f), 1.0f);

    // labels output (as float), 256 B/wave coalesced full lines.
    out[g * 64 + lane] = (float)label;

    // reg tile: 64 elems * 64 bins = 16 KB contiguous per wave-iteration.
    // 16 fully-coalesced dwordx4 stores (1 KB/instr, full 128-B lines -> no RMW).
    vfloat4* regv = (vfloat4*)(out + (size_t)N_ELEM + (size_t)g * (64 * KB)) + lane;
#pragma unroll
    for (int j = 0; j < 16; ++j) {
      const int src = (j << 2) + src_base;      // which lane's element this float4 belongs to
      const int lbl = __shfl(label, src, 64);
      const float dlt = __shfl(delta, src, 64);
      vfloat4 v;
      v.x = (kst + 0 == lbl) ? dlt : -1.0f;
      v.y = (kst + 1 == lbl) ? dlt : -1.0f;
      v.z = (kst + 2 == lbl) ? dlt : -1.0f;
      v.w = (kst + 3 == lbl) ? dlt : -1.0f;
      regv[j << 6] = v;
    }
  }
}

extern "C" void kernel_launch(void* const* d_in, const int* in_sizes, int n_in,
                              void* d_out, int out_size, void* d_ws, size_t ws_size,
                              hipStream_t stream) {
  const float* y = (const float*)d_in[0];
  const float* le = (const float*)d_in[1];
  const float* re = (const float*)d_in[2];
  float* out = (float*)d_out;

  const int n = in_sizes[0];          // 1048576
  const int ngroups = n / 64;         // 16384 wave-tiles
  const int blocks = 1024;            // 4096 waves, 4 tiles per wave (grid-stride)

  group_tokenizer_kernel<<<blocks, 256, 0, stream>>>(y, le, re, out, ngroups);
}